// Round 12
// baseline (169.560 us; speedup 1.0000x reference)
//
#include <hip/hip_runtime.h>

#define N_NODES 50000
#define D 64
#define BKT_SHIFT 10
#define BKT_NODES 1024
#define NBKT ((N_NODES + BKT_NODES - 1) / BKT_NODES)   // 49 buckets
#define CAP 18432      // per-bucket edge capacity (mean 16327, +16 sigma)
#define GPAD 32        // gcur padding: one counter per 128B line
#define XBLOCKS ((N_NODES * D / 4) / 256)               // 3125

typedef __attribute__((ext_vector_type(4))) float f4;
typedef __attribute__((ext_vector_type(4))) unsigned uv4;
typedef __attribute__((ext_vector_type(4))) unsigned short us4;
typedef __attribute__((ext_vector_type(8))) short bf16x8;
typedef __attribute__((ext_vector_type(4))) float f32x4;

// f32 -> bf16 round-to-nearest-even
static __device__ __forceinline__ unsigned short f2bf(float f) {
    unsigned u = __builtin_bit_cast(unsigned, f);
    unsigned r = (u + 0x7fffu + ((u >> 16) & 1u)) >> 16;
    return (unsigned short)r;
}
static __device__ __forceinline__ float bflo(unsigned w) {
    return __builtin_bit_cast(float, w << 16);
}
static __device__ __forceinline__ float bfhi(unsigned w) {
    return __builtin_bit_cast(float, w & 0xffff0000u);
}

// int64-vs-int32 probe, inlined per wave
static __device__ __forceinline__ int detect_is64(const unsigned* __restrict__ ei32) {
    int lane = threadIdx.x & 63;
    unsigned v = (lane < 32) ? ei32[2 * lane + 1] : 0u;
    return (__ballot(v != 0u) == 0ull) ? 1 : 0;
}

// load up to 4 edges (src,dst) starting at `base`; returns count (<=4)
static __device__ __forceinline__ int load_edges4(const unsigned* __restrict__ ei32,
                                                  int is64, int E, int base,
                                                  int* s, int* d) {
    if (base + 3 < E) {
        if (is64) {
            uv4 sa = *(const uv4*)&ei32[2 * base];
            uv4 sb = *(const uv4*)&ei32[2 * base + 4];
            uv4 da = *(const uv4*)&ei32[2 * (E + base)];
            uv4 db = *(const uv4*)&ei32[2 * (E + base) + 4];
            s[0] = (int)sa[0]; s[1] = (int)sa[2]; s[2] = (int)sb[0]; s[3] = (int)sb[2];
            d[0] = (int)da[0]; d[1] = (int)da[2]; d[2] = (int)db[0]; d[3] = (int)db[2];
        } else {
            uv4 sa = *(const uv4*)&ei32[base];
            uv4 da = *(const uv4*)&ei32[E + base];
            s[0] = (int)sa[0]; s[1] = (int)sa[1]; s[2] = (int)sa[2]; s[3] = (int)sa[3];
            d[0] = (int)da[0]; d[1] = (int)da[1]; d[2] = (int)da[2]; d[3] = (int)da[3];
        }
        return 4;
    }
    int c = 0;
    for (int e = base; e < E && e < base + 4; ++e, ++c) {
        s[c] = is64 ? (int)ei32[2 * e] : (int)ei32[e];
        d[c] = is64 ? (int)ei32[2 * (E + e)] : (int)ei32[E + e];
    }
    return c;
}

// ---------------------------------------------------------------------------
// 0. merged setup: blocks [0,XBLOCKS) x->bf16; [XBLOCKS,+4) W->bf16;
//    rest: bin edges into fixed-capacity per-bucket regions (gcur is
//    RELATIVE, pre-zeroed by hipMemsetAsync -> no ordering dependency).
// ---------------------------------------------------------------------------
__global__ __launch_bounds__(256) void setup_kernel(const float* __restrict__ x,
                                                    unsigned short* __restrict__ xb,
                                                    const float* __restrict__ Wl0,
                                                    const float* __restrict__ Wr0,
                                                    const float* __restrict__ Wl1,
                                                    const float* __restrict__ Wr1,
                                                    unsigned short* __restrict__ Wlb0,
                                                    unsigned short* __restrict__ Wrb0,
                                                    unsigned short* __restrict__ Wlb1,
                                                    unsigned short* __restrict__ Wrb1,
                                                    const unsigned* __restrict__ ei32,
                                                    int E, int* __restrict__ gcur,
                                                    unsigned* __restrict__ binned) {
    __shared__ int bc[NBKT];
    __shared__ int boff[NBKT];
    int b = blockIdx.x, tid = threadIdx.x;
    if (b < XBLOCKS) {
        int i = (b * 256 + tid) * 4;   // exact: N*D multiple of 1024
        f4 v = *(const f4*)&x[i];
        us4 o;
        o[0] = f2bf(v[0]); o[1] = f2bf(v[1]); o[2] = f2bf(v[2]); o[3] = f2bf(v[3]);
        *(us4*)&xb[i] = o;
        return;
    }
    if (b < XBLOCKS + 4) {
        int w = b - XBLOCKS;
        const float* src = (w == 0) ? Wl0 : (w == 1) ? Wr0 : (w == 2) ? Wl1 : Wr1;
        unsigned short* dst = (w == 0) ? Wlb0 : (w == 1) ? Wrb0 : (w == 2) ? Wlb1 : Wrb1;
        for (int i = tid * 4; i < 64 * 64; i += 1024) {
            f4 v = *(const f4*)&src[i];
            us4 o;
            o[0] = f2bf(v[0]); o[1] = f2bf(v[1]); o[2] = f2bf(v[2]); o[3] = f2bf(v[3]);
            *(us4*)&dst[i] = o;
        }
        return;
    }
    // ---- bin part ----
    int bb = b - (XBLOCKS + 4);
    if (tid < NBKT) bc[tid] = 0;
    __syncthreads();
    int is64 = detect_is64(ei32);
    int base = (bb * 256 + tid) * 8;
    int s[8], d[8];
    int c = 0;
    if (base < E) {
        c = load_edges4(ei32, is64, E, base, s, d);
        if (base + 4 < E) c += load_edges4(ei32, is64, E, base + 4, s + 4, d + 4);
    }
    for (int t = 0; t < c; ++t) atomicAdd(&bc[d[t] >> BKT_SHIFT], 1);
    __syncthreads();
    if (tid < NBKT) {
        int v = bc[tid];
        boff[tid] = v ? (tid * CAP + atomicAdd(&gcur[tid * GPAD], v)) : 0;
        bc[tid] = 0;
    }
    __syncthreads();
    for (int t = 0; t < c; ++t) {
        int bkt = d[t] >> BKT_SHIFT;
        int pos = boff[bkt] + atomicAdd(&bc[bkt], 1);
        if (pos < (bkt + 1) * CAP)   // overflow guard (16-sigma margin)
            binned[pos] = ((unsigned)(d[t] & (BKT_NODES - 1)) << 16) | (unsigned)s[t];
    }
}

// ---------------------------------------------------------------------------
// 1. build: one 1024-thread block per bucket (1 node per thread).
//    LDS node histogram, shfl scan, write (beg,deg), scatter ssrc (ushort)
//    within the bucket's ~32KB window.
// ---------------------------------------------------------------------------
__global__ __launch_bounds__(1024) void build_kernel(const unsigned* __restrict__ binned,
                                                     const int* __restrict__ gcur,
                                                     int2* __restrict__ rp2,
                                                     unsigned short* __restrict__ ssrc, int n) {
    __shared__ int nc[BKT_NODES];
    __shared__ int wpart[16];
    int b = blockIdx.x;
    int tid = threadIdx.x;
    int ebase = b * CAP;
    int cnt = gcur[b * GPAD];
    if (cnt > CAP) cnt = CAP;
    int eend = ebase + cnt;
    nc[tid] = 0;
    __syncthreads();
    for (int i = ebase + tid; i < eend; i += 1024)
        atomicAdd(&nc[binned[i] >> 16], 1);
    __syncthreads();
    int v = nc[tid];
    int lane = tid & 63, wv = tid >> 6;
    int incl = v;
#pragma unroll
    for (int off = 1; off < 64; off <<= 1) {
        int t = __shfl_up(incl, off);
        if (lane >= off) incl += t;
    }
    if (lane == 63) wpart[wv] = incl;
    __syncthreads();
    int pre = 0;
    for (int w2 = 0; w2 < wv; ++w2) pre += wpart[w2];
    int run = ebase + pre + incl - v;   // exclusive global position
    int node = b * BKT_NODES + tid;
    nc[tid] = run;                      // becomes the scatter cursor
    if (node < n) rp2[node] = make_int2(run, v);
    __syncthreads();
    for (int i = ebase + tid; i < eend; i += 1024) {
        unsigned u = binned[i];
        int pos = atomicAdd(&nc[u >> 16], 1);
        ssrc[pos] = (unsigned short)(u & 0xffffu);
    }
}

// ---------------------------------------------------------------------------
// 2. fused SAGE layer, split-K: block = 256 threads = 4 waves = 16 nodes.
//    Each wave aggregates a QUARTER of every node's edge list. 4-edge inner
//    unroll: all 4 ssrc index loads issue first (independent), then 8
//    independent 16B row loads -> ~12 outstanding VMEM per wave vs 6 before.
//    Self-row + W-fragments + bias hoisted above the gather to overlap.
//    Partials combined via conflict-free LDS; wave w computes o-tile w.
// ---------------------------------------------------------------------------
template <bool RELU, bool LAST>
__global__ __launch_bounds__(256) void sage_fused(const unsigned short* __restrict__ xb,
                                                  const int2* __restrict__ rp2,
                                                  const unsigned short* __restrict__ ssrc,
                                                  const unsigned short* __restrict__ Wlb,
                                                  const float* __restrict__ bl,
                                                  const unsigned short* __restrict__ Wrb,
                                                  float* __restrict__ out,
                                                  unsigned short* __restrict__ ob, int n) {
    __shared__ f4 lred[4][4][64];   // [q][wave][lane] -> lane-contiguous 16B
    int tid = threadIdx.x;
    int wv = tid >> 6;
    int lane = tid & 63;
    int nb = blockIdx.x * 16;       // grid exact: N % 16 == 0
    int row = lane & 15;
    int half = lane >> 4;
    int koff = half * 8;
    int node = nb + row;
    int2 bd = rp2[node];
    int deg = bd.y;
    int chunk = (deg + 3) >> 2;     // this wave's share of the edge list
    int beg = bd.x + wv * chunk;
    int end = bd.x + deg;
    if (end > beg + chunk) end = beg + chunk;

    // hoisted independent loads: self row, W fragments, bias (overlap gather)
    bf16x8 x0 = *(const bf16x8*)&xb[(size_t)node * 64 + koff];
    bf16x8 x1 = *(const bf16x8*)&xb[(size_t)node * 64 + 32 + koff];
    int o = wv * 16 + row;
    bf16x8 wl0 = *(const bf16x8*)&Wlb[(size_t)o * 64 + koff];
    bf16x8 wl1 = *(const bf16x8*)&Wlb[(size_t)o * 64 + 32 + koff];
    bf16x8 wr0 = *(const bf16x8*)&Wrb[(size_t)o * 64 + koff];
    bf16x8 wr1 = *(const bf16x8*)&Wrb[(size_t)o * 64 + 32 + koff];
    float bv = bl[o];

    f4 acc4[4];
#pragma unroll
    for (int q = 0; q < 4; ++q) acc4[q] = (f4){0.f, 0.f, 0.f, 0.f};

    int e = beg;
    for (; e + 3 < end; e += 4) {
        // batch the 4 index loads (independent), then 8 independent row loads
        int s0 = ssrc[e], s1 = ssrc[e + 1], s2 = ssrc[e + 2], s3 = ssrc[e + 3];
        uv4 r0 = *(const uv4*)(xb + (size_t)s0 * 64 + koff);
        uv4 r1 = *(const uv4*)(xb + (size_t)s0 * 64 + 32 + koff);
        uv4 r2 = *(const uv4*)(xb + (size_t)s1 * 64 + koff);
        uv4 r3 = *(const uv4*)(xb + (size_t)s1 * 64 + 32 + koff);
        uv4 r4 = *(const uv4*)(xb + (size_t)s2 * 64 + koff);
        uv4 r5 = *(const uv4*)(xb + (size_t)s2 * 64 + 32 + koff);
        uv4 r6 = *(const uv4*)(xb + (size_t)s3 * 64 + koff);
        uv4 r7 = *(const uv4*)(xb + (size_t)s3 * 64 + 32 + koff);
#pragma unroll
        for (int q = 0; q < 2; ++q) {
            acc4[q][0] += (bflo(r0[2 * q]) + bflo(r2[2 * q])) + (bflo(r4[2 * q]) + bflo(r6[2 * q]));
            acc4[q][1] += (bfhi(r0[2 * q]) + bfhi(r2[2 * q])) + (bfhi(r4[2 * q]) + bfhi(r6[2 * q]));
            acc4[q][2] += (bflo(r0[2 * q + 1]) + bflo(r2[2 * q + 1])) + (bflo(r4[2 * q + 1]) + bflo(r6[2 * q + 1]));
            acc4[q][3] += (bfhi(r0[2 * q + 1]) + bfhi(r2[2 * q + 1])) + (bfhi(r4[2 * q + 1]) + bfhi(r6[2 * q + 1]));
            acc4[2 + q][0] += (bflo(r1[2 * q]) + bflo(r3[2 * q])) + (bflo(r5[2 * q]) + bflo(r7[2 * q]));
            acc4[2 + q][1] += (bfhi(r1[2 * q]) + bfhi(r3[2 * q])) + (bfhi(r5[2 * q]) + bfhi(r7[2 * q]));
            acc4[2 + q][2] += (bflo(r1[2 * q + 1]) + bflo(r3[2 * q + 1])) + (bflo(r5[2 * q + 1]) + bflo(r7[2 * q + 1]));
            acc4[2 + q][3] += (bfhi(r1[2 * q + 1]) + bfhi(r3[2 * q + 1])) + (bfhi(r5[2 * q + 1]) + bfhi(r7[2 * q + 1]));
        }
    }
    for (; e < end; ++e) {
        int s0 = ssrc[e];
        uv4 r0 = *(const uv4*)(xb + (size_t)s0 * 64 + koff);
        uv4 r1 = *(const uv4*)(xb + (size_t)s0 * 64 + 32 + koff);
#pragma unroll
        for (int q = 0; q < 2; ++q) {
            acc4[q][0] += bflo(r0[2 * q]);
            acc4[q][1] += bfhi(r0[2 * q]);
            acc4[q][2] += bflo(r0[2 * q + 1]);
            acc4[q][3] += bfhi(r0[2 * q + 1]);
            acc4[2 + q][0] += bflo(r1[2 * q]);
            acc4[2 + q][1] += bfhi(r1[2 * q]);
            acc4[2 + q][2] += bflo(r1[2 * q + 1]);
            acc4[2 + q][3] += bfhi(r1[2 * q + 1]);
        }
    }

    // cross-wave combine: write own partial, read the other three
#pragma unroll
    for (int q = 0; q < 4; ++q) lred[q][wv][lane] = acc4[q];
    __syncthreads();
#pragma unroll
    for (int w2 = 0; w2 < 4; ++w2) {
        if (w2 == wv) continue;
#pragma unroll
        for (int q = 0; q < 4; ++q) acc4[q] += lred[q][w2][lane];
    }

    float inv = 1.0f / (float)(deg > 1 ? deg : 1);
    uv4 pa0, pa1;
#pragma unroll
    for (int q = 0; q < 2; ++q) {
        pa0[2 * q]     = (unsigned)f2bf(acc4[q][0] * inv) |
                         ((unsigned)f2bf(acc4[q][1] * inv) << 16);
        pa0[2 * q + 1] = (unsigned)f2bf(acc4[q][2] * inv) |
                         ((unsigned)f2bf(acc4[q][3] * inv) << 16);
        pa1[2 * q]     = (unsigned)f2bf(acc4[2 + q][0] * inv) |
                         ((unsigned)f2bf(acc4[2 + q][1] * inv) << 16);
        pa1[2 * q + 1] = (unsigned)f2bf(acc4[2 + q][2] * inv) |
                         ((unsigned)f2bf(acc4[2 + q][3] * inv) << 16);
    }
    bf16x8 a0 = __builtin_bit_cast(bf16x8, pa0);
    bf16x8 a1 = __builtin_bit_cast(bf16x8, pa1);

    f32x4 accd = (f32x4){bv, bv, bv, bv};
    accd = __builtin_amdgcn_mfma_f32_16x16x32_bf16(a0, wl0, accd, 0, 0, 0);
    accd = __builtin_amdgcn_mfma_f32_16x16x32_bf16(a1, wl1, accd, 0, 0, 0);
    accd = __builtin_amdgcn_mfma_f32_16x16x32_bf16(x0, wr0, accd, 0, 0, 0);
    accd = __builtin_amdgcn_mfma_f32_16x16x32_bf16(x1, wr1, accd, 0, 0, 0);

#pragma unroll
    for (int r = 0; r < 4; ++r) {
        float v = accd[r];
        if (RELU) v = fmaxf(v, 0.f);
        int nd = nb + half * 4 + r;
        if (LAST) out[(size_t)nd * 64 + o] = v;
        else      ob[(size_t)nd * 64 + o] = f2bf(v);
    }
}

// ---------------------------------------------------------------------------
extern "C" void kernel_launch(void* const* d_in, const int* in_sizes, int n_in,
                              void* d_out, int out_size, void* d_ws, size_t ws_size,
                              hipStream_t stream) {
    const float* x      = (const float*)d_in[0];
    const unsigned* ei  = (const unsigned*)d_in[1];
    const float* Wl0    = (const float*)d_in[2];
    const float* bl0    = (const float*)d_in[3];
    const float* Wr0    = (const float*)d_in[4];
    const float* Wl1    = (const float*)d_in[5];
    const float* bl1    = (const float*)d_in[6];
    const float* Wr1    = (const float*)d_in[7];
    float* out          = (float*)d_out;

    const int N = N_NODES;
    const int E = in_sizes[1] / 2;

    char* w = (char*)d_ws;
    auto take = [&](size_t bytes) {
        char* p = w;
        w += (bytes + 255) & ~(size_t)255;
        return p;
    };
    int*            gcur   = (int*)take((size_t)NBKT * GPAD * sizeof(int));
    unsigned*       binned = (unsigned*)take((size_t)NBKT * CAP * sizeof(unsigned));
    int2*           rp2    = (int2*)take((size_t)N * sizeof(int2));
    unsigned short* ssrc   = (unsigned short*)take((size_t)NBKT * CAP * sizeof(unsigned short));
    unsigned short* xb     = (unsigned short*)take((size_t)N * D * sizeof(unsigned short));
    unsigned short* hb     = (unsigned short*)take((size_t)N * D * sizeof(unsigned short));
    unsigned short* Wlb0   = (unsigned short*)take((size_t)D * D * sizeof(unsigned short));
    unsigned short* Wrb0   = (unsigned short*)take((size_t)D * D * sizeof(unsigned short));
    unsigned short* Wlb1   = (unsigned short*)take((size_t)D * D * sizeof(unsigned short));
    unsigned short* Wrb1   = (unsigned short*)take((size_t)D * D * sizeof(unsigned short));

    hipMemsetAsync(gcur, 0, (size_t)NBKT * GPAD * sizeof(int), stream);
    int edgeBlocks = (E + 2047) / 2048;   // 8 edges/thread
    setup_kernel<<<XBLOCKS + 4 + edgeBlocks, 256, 0, stream>>>(
        x, xb, Wl0, Wr0, Wl1, Wr1, Wlb0, Wrb0, Wlb1, Wrb1, ei, E, gcur, binned);
    build_kernel<<<NBKT, 1024, 0, stream>>>(binned, gcur, rp2, ssrc, N);

    int fusedBlocks = (N + 15) / 16;      // 16 nodes per 256-thread block
    sage_fused<true, false><<<fusedBlocks, 256, 0, stream>>>(xb, rp2, ssrc, Wlb0, bl0, Wrb0,
                                                             nullptr, hb, N);
    sage_fused<false, true><<<fusedBlocks, 256, 0, stream>>>(hb, rp2, ssrc, Wlb1, bl1, Wrb1,
                                                             out, nullptr, N);
}